// Round 7
// baseline (294.410 us; speedup 1.0000x reference)
//
#include <hip/hip_runtime.h>
#include <hip/hip_bf16.h>
#include <math.h>

// B=4, T=2048, C=1024, H=16, D=64. All dims divide tiles exactly.
typedef __bf16 bf16;
typedef __bf16 bf16x8 __attribute__((ext_vector_type(8)));
typedef __bf16 bf16x4 __attribute__((ext_vector_type(4)));
typedef float  f32x4  __attribute__((ext_vector_type(4)));

// async 16B/lane global->LDS. lds base must be wave-uniform; HW adds lane*16.
__device__ __forceinline__ void gld_lds16(const bf16* g, bf16* l) {
    void* gv = (void*)g;  // drop const
    __builtin_amdgcn_global_load_lds(
        (__attribute__((address_space(1))) void*)gv,
        (__attribute__((address_space(3))) void*)l, 16, 0, 0);
}

// ---------------- fp32 -> bf16 elementwise cast ----------------
__global__ void k_cvt_bf16(const float* __restrict__ in, bf16* __restrict__ out, int n4) {
    int i = blockIdx.x * blockDim.x + threadIdx.x;
    if (i < n4) {
        float4 v = ((const float4*)in)[i];
        bf16x4 o;
        o[0] = (bf16)v.x; o[1] = (bf16)v.y; o[2] = (bf16)v.z; o[3] = (bf16)v.w;
        ((bf16x4*)out)[i] = o;
    }
}

// ---------------- fp32 [R][C] -> bf16 [C][R] transpose+cast ----------------
// grid (C/64, R/64), block 256
__global__ void k_transpose_cvt(const float* __restrict__ in, bf16* __restrict__ out,
                                int R, int C) {
    __shared__ float tile[64][68];
    int c0 = blockIdx.x * 64, r0 = blockIdx.y * 64;
    int tid = threadIdx.x;
#pragma unroll
    for (int i = 0; i < 4; ++i) {            // 1024 float4 chunks
        int chunk = tid + i * 256;
        int r = chunk >> 4, c4 = (chunk & 15) * 4;
        float4 v = *(const float4*)(in + (size_t)(r0 + r) * C + c0 + c4);
        tile[r][c4 + 0] = v.x; tile[r][c4 + 1] = v.y;
        tile[r][c4 + 2] = v.z; tile[r][c4 + 3] = v.w;
    }
    __syncthreads();
#pragma unroll
    for (int i = 0; i < 2; ++i) {            // 512 chunks of 8 bf16
        int chunk = tid + i * 256;
        int c = chunk >> 3, k8 = (chunk & 7) * 8;
        bf16x8 v;
#pragma unroll
        for (int j = 0; j < 8; ++j) v[j] = (bf16)tile[k8 + j][c];
        *(bf16x8*)(out + (size_t)(c0 + c) * R + r0 + k8) = v;
    }
}

// ---------------- V slice of qkv -> vt[(bh*64+d)*2048 + t] ----------------
// grid (T/64, B*H), block 256. Also zeroes the attn work-steal counter
// (stream-ordered between GEMM1 and attn).
__global__ void k_transpose_v(const bf16* __restrict__ qkv, bf16* __restrict__ vt,
                              int* __restrict__ ctr) {
    __shared__ bf16 tile[64][72];
    if (threadIdx.x == 0 && blockIdx.x == 0 && blockIdx.y == 0) *ctr = 0;
    int bh = blockIdx.y, b = bh >> 4, h = bh & 15;
    int t0 = blockIdx.x * 64;
    int tid = threadIdx.x;
    const bf16* src = qkv + (size_t)(b * 2048 + t0) * 3072 + 2048 + h * 64;
#pragma unroll
    for (int i = 0; i < 2; ++i) {
        int chunk = tid + i * 256;
        int t = chunk >> 3, d8 = (chunk & 7) * 8;
        bf16x8 v = *(const bf16x8*)(src + (size_t)t * 3072 + d8);
#pragma unroll
        for (int j = 0; j < 8; ++j) tile[t][d8 + j] = v[j];
    }
    __syncthreads();
#pragma unroll
    for (int i = 0; i < 2; ++i) {
        int chunk = tid + i * 256;
        int d = chunk >> 3, t8 = (chunk & 7) * 8;
        bf16x8 v;
#pragma unroll
        for (int j = 0; j < 8; ++j) v[j] = tile[t8 + j][d];
        *(bf16x8*)(vt + ((size_t)bh * 64 + d) * 2048 + t0 + t8) = v;
    }
}

// ---------------- GEMM: C[M][N] = A[M][K] * Bt[N][K]^T + bias ----------------
// 128x128 block tile, 4 waves (2x2) of 64x64, BK=64 kf-split LDS [2][128][32]
// (bank-uniform), global_load_lds width=16 staging, mfma 16x16x32 bf16.
template <bool OUT_BF16>
__global__ __launch_bounds__(256, 2) void k_gemm(
    const bf16* __restrict__ A, const bf16* __restrict__ Bt,
    const float* __restrict__ bias, void* __restrict__ Cout,
    int M, int N, int K) {
    __shared__ __align__(16) bf16 lA[2][4096];
    __shared__ __align__(16) bf16 lB[2][4096];
    int tid = threadIdx.x;
    int wid = tid >> 6, lane = tid & 63;
    int quad = lane >> 4, l16 = lane & 15;
    int bm = blockIdx.y * 128, bn = blockIdx.x * 128;
    int wm = (wid >> 1) * 64, wn = (wid & 1) * 64;

    f32x4 zero = {0.f, 0.f, 0.f, 0.f};
    f32x4 acc[4][4];
#pragma unroll
    for (int i = 0; i < 4; ++i)
#pragma unroll
        for (int j = 0; j < 4; ++j) acc[i][j] = zero;

    for (int k0 = 0; k0 < K; k0 += 64) {
        __syncthreads();
#pragma unroll
        for (int i = 0; i < 4; ++i) {
            int j = (wid * 4 + i) * 64 + lane;          // 0..1023
            int kf = j >> 9, row = (j & 511) >> 2, c8 = (j & 3) * 8;
            gld_lds16(A  + (size_t)(bm + row) * K + k0 + kf * 32 + c8, &lA[0][0] + (wid * 4 + i) * 512);
            gld_lds16(Bt + (size_t)(bn + row) * K + k0 + kf * 32 + c8, &lB[0][0] + (wid * 4 + i) * 512);
        }
        __syncthreads();
#pragma unroll
        for (int kk = 0; kk < 2; ++kk) {
            bf16x8 af[4], bg[4];
#pragma unroll
            for (int i = 0; i < 4; ++i) {
                af[i] = *(const bf16x8*)(&lA[kk][(wm + i * 16 + l16) * 32 + quad * 8]);
                bg[i] = *(const bf16x8*)(&lB[kk][(wn + i * 16 + l16) * 32 + quad * 8]);
            }
#pragma unroll
            for (int i = 0; i < 4; ++i)
#pragma unroll
                for (int j = 0; j < 4; ++j)
                    acc[i][j] = __builtin_amdgcn_mfma_f32_16x16x32_bf16(af[i], bg[j], acc[i][j], 0, 0, 0);
        }
    }
#pragma unroll
    for (int i = 0; i < 4; ++i) {
#pragma unroll
        for (int j = 0; j < 4; ++j) {
            int col = bn + wn + j * 16 + l16;
            float bv = bias ? bias[col] : 0.f;
#pragma unroll
            for (int r = 0; r < 4; ++r) {
                int row = bm + wm + i * 16 + quad * 4 + r;
                float v = acc[i][j][r] + bv;
                if (OUT_BF16) ((bf16*)Cout)[(size_t)row * N + col] = (bf16)v;
                else          ((float*)Cout)[(size_t)row * N + col] = v;
            }
        }
    }
}

// ---------------- flash attention (v12: v11 + dynamic work-stealing) ---------
// v11 measured 79.8us with OccupancyPercent 27.5 vs 50 static: grid==capacity
// (1024 = 4/CU exactly, no backfill) + 16:1 per-block work spread => CU
// makespan ~ max(resident sums) ~ 1.8x mean. Fix is mapping-independent
// (round-3 lesson): blocks PULL items (bh,qb) from a global atomic counter,
// heavy-first order => greedy LPT balance; last items are the 2-iter qb=0s.
// Inter-item safety: the s_item __syncthreads drains each wave's in-flight
// restage loads (compiler emits vmcnt(0) before s_barrier) before the next
// item's stageK(0,0); s_item write/read separated by the k-loop barriers.
// Core per-item body identical to v11 (counted-vmcnt V, MINIT C-operand,
// kf-split lP, XOR-swizzled K both-sides, exp2 domain, MFMA-ones rowsum).
__global__ __launch_bounds__(256, 4) void k_attn(
    const bf16* __restrict__ qkv,   // [B*T][3072]
    const bf16* __restrict__ vt,    // [(bh*64+d)*2048 + t]
    bf16* __restrict__ y,           // [B*T][1024]
    int* __restrict__ ctr) {
    __shared__ __align__(16) bf16 lK[2][4096];
    __shared__ __align__(16) bf16 lV[4096];
    __shared__ __align__(16) bf16 lP[4][32 * 36];   // [q 32][t 32+4 pad] per kf
    __shared__ int s_item;

    const int T = 2048, CQ = 3072;
    int tid = threadIdx.x, wid = tid >> 6, lane = tid & 63;
    int quad = lane >> 4, l16 = lane & 15;
    bf16* lPw = lP[wid];

    const float QSCALE = 0.125f * 1.44269504088896341f;
    f32x4 zero = {0.f, 0.f, 0.f, 0.f};
    f32x4 minit = {-14.4269504089f, -14.4269504089f, -14.4269504089f, -14.4269504089f};
    bf16x8 ones;
#pragma unroll
    for (int j = 0; j < 8; ++j) ones[j] = (bf16)1.0f;

    for (;;) {
        if (tid == 0) s_item = atomicAdd(ctr, 1);
        __syncthreads();                       // broadcast + drain stale loads
        int id = s_item;
        if (id >= 1024) break;
        int bh = ((id & 7) << 3) | ((id >> 3) & 7);
        int qb = 15 - (id >> 6);               // heavy-first item order
        int b = bh >> 4, h = bh & 15;
        int q0 = qb * 128;
        int rb = qb * 4 + wid;                 // this wave's 32-row block idx
        int mdiag = rb >> 1;                   // k-tile containing diagonal
        int ntiles = qb * 2 + 2;               // tiles staged for this item

        const bf16* qbase = qkv + (size_t)(b * T + q0 + wid * 32) * CQ + h * 64;
        const bf16* kbase = qkv + (size_t)(b * T) * CQ + 1024 + h * 64;
        const bf16* vbase = vt + (size_t)bh * 64 * T;

        // stage K tile kt into buffer buf: [row 64][col 64] bf16, 16B chunk
        // index XOR-swizzled by row&7 on the GLOBAL side (LDS dest linear).
        auto stageK = [&](int kt, int buf) {
            int t0 = kt * 64;
#pragma unroll
            for (int i = 0; i < 2; ++i) {
                int j = (wid * 2 + i) * 64 + lane;     // 0..511 16B-chunk id
                int r = j >> 3;                        // row (t)
                int cs = ((j ^ r) & 7) * 8;            // swizzled col offset
                gld_lds16(kbase + (size_t)(t0 + r) * CQ + cs, &lK[buf][(wid * 2 + i) * 512]);
            }
        };
        auto stageV = [&](int kt) {
            int t0 = kt * 64;
#pragma unroll
            for (int i = 0; i < 2; ++i) {
                int j = (wid * 2 + i) * 64 + lane;
                int r = j >> 3;                        // row (d)
                int cs = ((j ^ r) & 7) * 8;
                gld_lds16(vbase + (size_t)r * T + t0 + cs, &lV[(wid * 2 + i) * 512]);
            }
        };

        // Q B-frags, prescaled into exp2 domain
        bf16x8 qf[2][2];
#pragma unroll
        for (int qi = 0; qi < 2; ++qi)
#pragma unroll
            for (int kf = 0; kf < 2; ++kf) {
                bf16x8 v = *(const bf16x8*)(qbase + (size_t)(qi * 16 + l16) * CQ + kf * 32 + quad * 8);
#pragma unroll
                for (int j = 0; j < 8; ++j) v[j] = (bf16)((float)v[j] * QSCALE);
                qf[qi][kf] = v;
            }

        f32x4 o[2][4];
        f32x4 ls[2];
#pragma unroll
        for (int qi = 0; qi < 2; ++qi) {
            ls[qi] = zero;
#pragma unroll
            for (int i = 0; i < 4; ++i) o[qi][i] = zero;
        }

        stageK(0, 0);                          // 2 loads outstanding
        for (int kt = 0; kt < ntiles; ++kt) {
            __syncthreads();                   // K(kt) landed; V(kt-1) consumed
            stageV(kt);                        // 2 loads (oldest outstanding)
            int knext = (kt + 1 < ntiles) ? kt + 1 : kt;   // last: restage kt
            stageK(knext, (kt + 1) & 1);       // 2 loads (stay in flight)
            if (kt > mdiag) continue;          // barrier-only iteration
            const bf16* Kb = lK[kt & 1];
            bool diag = (kt == mdiag);
            bool half = diag && !(rb & 1);     // even rb: only t 0..31 live
            int in_hi = half ? 2 : 4;

            // S^T = K (Q*log2e/8)^T - 10*log2e; MINIT as first MFMA C-operand
            f32x4 s[2][4];
#pragma unroll
            for (int in = 0; in < 4; ++in) {
                if (in >= in_hi) break;
                bf16x8 kb0 = *(const bf16x8*)(Kb + (in * 16 + l16) * 64 + ((quad ^ (l16 & 7)) * 8));
                bf16x8 kb1 = *(const bf16x8*)(Kb + (in * 16 + l16) * 64 + (((4 + quad) ^ (l16 & 7)) * 8));
#pragma unroll
                for (int qi = 0; qi < 2; ++qi) {
                    f32x4 t0 = __builtin_amdgcn_mfma_f32_16x16x32_bf16(kb0, qf[qi][0], minit, 0, 0, 0);
                    s[qi][in] = __builtin_amdgcn_mfma_f32_16x16x32_bf16(kb1, qf[qi][1], t0, 0, 0, 0);
                }
            }

            int rl0 = (rb * 32) - kt * 64;     // q offset rel to tile t-base
#pragma unroll
            for (int kf = 0; kf < 2; ++kf) {
                // p = exp2(S) for this kf's 32 t-cols; causal mask on diag
#pragma unroll
                for (int qi = 0; qi < 2; ++qi) {
                    int qloc = rl0 + qi * 16 + l16;
#pragma unroll
                    for (int in2 = 0; in2 < 2; ++in2) {
                        int in = kf * 2 + in2;
                        bf16x4 pk4;
                        if (in >= in_hi) {
                            pk4[0] = pk4[1] = pk4[2] = pk4[3] = (bf16)0.f;
                        } else {
#pragma unroll
                            for (int r = 0; r < 4; ++r) {
                                float e = __builtin_amdgcn_exp2f(s[qi][in][r]);
                                if (diag) {
                                    int tloc = kf * 32 + in2 * 16 + quad * 4 + r;
                                    if (tloc > qloc) e = 0.f;
                                }
                                pk4[r] = (bf16)e;
                            }
                        }
                        *(bf16x4*)(lPw + (qi * 16 + l16) * 36 + in2 * 16 + quad * 4) = pk4;
                    }
                }
                if (kf == 0)  // V(kt)'s 2 loads are oldest; K prefetch stays
                              // in flight (T4 counted vmcnt, never 0 mid-loop)
                    asm volatile("s_waitcnt vmcnt(2)" ::: "memory");
                // V B-frags for this kf (swizzled reads from single buffer)
                bf16x8 vb[4];
#pragma unroll
                for (int dn = 0; dn < 4; ++dn)
                    vb[dn] = *(const bf16x8*)(lV + (dn * 16 + l16) * 64 + (((kf * 4 + quad) ^ (l16 & 7)) * 8));
                // P A-frags (same-wave LDS), O += P V, rowsum += P*ones
#pragma unroll
                for (int qi = 0; qi < 2; ++qi) {
                    bf16x8 pa = *(const bf16x8*)(lPw + (qi * 16 + l16) * 36 + quad * 8);
                    ls[qi] = __builtin_amdgcn_mfma_f32_16x16x32_bf16(pa, ones, ls[qi], 0, 0, 0);
#pragma unroll
                    for (int dn = 0; dn < 4; ++dn)
                        o[qi][dn] = __builtin_amdgcn_mfma_f32_16x16x32_bf16(pa, vb[dn], o[qi][dn], 0, 0, 0);
                }
            }
        }

        // epilogue: ls[qi][r] = rowsum for q=quad*4+r — same C-layout rows as
        // o[qi][dn][r]; no cross-lane reduction needed.
#pragma unroll
        for (int qi = 0; qi < 2; ++qi)
#pragma unroll
            for (int r = 0; r < 4; ++r) {
                float li = 1.f / ls[qi][r];
                int row = q0 + wid * 32 + qi * 16 + quad * 4 + r;
#pragma unroll
                for (int dn = 0; dn < 4; ++dn) {
                    float v = o[qi][dn][r] * li;
                    y[(size_t)(b * T + row) * 1024 + h * 64 + dn * 16 + l16] = (bf16)v;
                }
            }
    }
}

extern "C" void kernel_launch(void* const* d_in, const int* in_sizes, int n_in,
                              void* d_out, int out_size, void* d_ws, size_t ws_size,
                              hipStream_t stream) {
    const float* x     = (const float*)d_in[0];
    const float* w_qkv = (const float*)d_in[1];
    const float* b_qkv = (const float*)d_in[2];
    const float* w_out = (const float*)d_in[3];
    const float* b_out = (const float*)d_in[4];
    float* out = (float*)d_out;

    const int B = 4, T = 2048, C = 1024, H = 16;
    const int M = B * T;  // 8192

    // workspace layout (88 MB total); vt aliases xb (xb dead after GEMM1).
    // Work-steal counter: last 4B of wqkvT (dead after GEMM1; zeroed by
    // k_transpose_v which runs between GEMM1 and attn).
    char* ws = (char*)d_ws;
    bf16* xb    = (bf16*)(ws);                        // 16 MB
    bf16* wqkvT = (bf16*)(ws + (16ull << 20));        //  6 MB
    bf16* woutT = (bf16*)(ws + (22ull << 20));        //  2 MB
    bf16* qkvb  = (bf16*)(ws + (24ull << 20));        // 48 MB
    bf16* yb    = (bf16*)(ws + (72ull << 20));        // 16 MB
    bf16* vtb   = xb;
    int*  ctr   = (int*)(ws + (22ull << 20) - 4);

    k_cvt_bf16<<<(M * C / 4 + 255) / 256, 256, 0, stream>>>(x, xb, M * C / 4);
    k_transpose_cvt<<<dim3(3 * C / 64, C / 64), 256, 0, stream>>>(w_qkv, wqkvT, C, 3 * C);
    k_transpose_cvt<<<dim3(C / 64, C / 64), 256, 0, stream>>>(w_out, woutT, C, C);
    k_gemm<true><<<dim3(3 * C / 128, M / 128), 256, 0, stream>>>(xb, wqkvT, b_qkv, qkvb, M, 3 * C, C);
    k_transpose_v<<<dim3(T / 64, B * H), 256, 0, stream>>>(qkvb, vtb, ctr);
    k_attn<<<dim3(1024, 1), 256, 0, stream>>>(qkvb, vtb, yb, ctr);
    k_gemm<false><<<dim3(C / 128, M / 128), 256, 0, stream>>>(yb, woutT, b_out, out, M, C, C);
}

// Round 8
// 273.658 us; speedup vs baseline: 1.0758x; 1.0758x over previous
//
#include <hip/hip_runtime.h>
#include <hip/hip_bf16.h>
#include <math.h>

// B=4, T=2048, C=1024, H=16, D=64. All dims divide tiles exactly.
typedef __bf16 bf16;
typedef __bf16 bf16x8 __attribute__((ext_vector_type(8)));
typedef __bf16 bf16x4 __attribute__((ext_vector_type(4)));
typedef float  f32x4  __attribute__((ext_vector_type(4)));

// async 16B/lane global->LDS. lds base must be wave-uniform; HW adds lane*16.
__device__ __forceinline__ void gld_lds16(const bf16* g, bf16* l) {
    void* gv = (void*)g;  // drop const
    __builtin_amdgcn_global_load_lds(
        (__attribute__((address_space(1))) void*)gv,
        (__attribute__((address_space(3))) void*)l, 16, 0, 0);
}

// ---------------- fp32 -> bf16 elementwise cast ----------------
__global__ void k_cvt_bf16(const float* __restrict__ in, bf16* __restrict__ out, int n4) {
    int i = blockIdx.x * blockDim.x + threadIdx.x;
    if (i < n4) {
        float4 v = ((const float4*)in)[i];
        bf16x4 o;
        o[0] = (bf16)v.x; o[1] = (bf16)v.y; o[2] = (bf16)v.z; o[3] = (bf16)v.w;
        ((bf16x4*)out)[i] = o;
    }
}

// ---------------- fp32 [R][C] -> bf16 [C][R] transpose+cast ----------------
// grid (C/64, R/64), block 256
__global__ void k_transpose_cvt(const float* __restrict__ in, bf16* __restrict__ out,
                                int R, int C) {
    __shared__ float tile[64][68];
    int c0 = blockIdx.x * 64, r0 = blockIdx.y * 64;
    int tid = threadIdx.x;
#pragma unroll
    for (int i = 0; i < 4; ++i) {            // 1024 float4 chunks
        int chunk = tid + i * 256;
        int r = chunk >> 4, c4 = (chunk & 15) * 4;
        float4 v = *(const float4*)(in + (size_t)(r0 + r) * C + c0 + c4);
        tile[r][c4 + 0] = v.x; tile[r][c4 + 1] = v.y;
        tile[r][c4 + 2] = v.z; tile[r][c4 + 3] = v.w;
    }
    __syncthreads();
#pragma unroll
    for (int i = 0; i < 2; ++i) {            // 512 chunks of 8 bf16
        int chunk = tid + i * 256;
        int c = chunk >> 3, k8 = (chunk & 7) * 8;
        bf16x8 v;
#pragma unroll
        for (int j = 0; j < 8; ++j) v[j] = (bf16)tile[k8 + j][c];
        *(bf16x8*)(out + (size_t)(c0 + c) * R + r0 + k8) = v;
    }
}

// ---------------- V slice of qkv -> vt[(bh*64+d)*2048 + t] ----------------
// grid (T/64, B*H), block 256
__global__ void k_transpose_v(const bf16* __restrict__ qkv, bf16* __restrict__ vt) {
    __shared__ bf16 tile[64][72];
    int bh = blockIdx.y, b = bh >> 4, h = bh & 15;
    int t0 = blockIdx.x * 64;
    int tid = threadIdx.x;
    const bf16* src = qkv + (size_t)(b * 2048 + t0) * 3072 + 2048 + h * 64;
#pragma unroll
    for (int i = 0; i < 2; ++i) {
        int chunk = tid + i * 256;
        int t = chunk >> 3, d8 = (chunk & 7) * 8;
        bf16x8 v = *(const bf16x8*)(src + (size_t)t * 3072 + d8);
#pragma unroll
        for (int j = 0; j < 8; ++j) tile[t][d8 + j] = v[j];
    }
    __syncthreads();
#pragma unroll
    for (int i = 0; i < 2; ++i) {
        int chunk = tid + i * 256;
        int d = chunk >> 3, t8 = (chunk & 7) * 8;
        bf16x8 v;
#pragma unroll
        for (int j = 0; j < 8; ++j) v[j] = tile[t8 + j][d];
        *(bf16x8*)(vt + ((size_t)bh * 64 + d) * 2048 + t0 + t8) = v;
    }
}

// ---------------- GEMM: C[M][N] = A[M][K] * Bt[N][K]^T + bias ----------------
// 128x128 block tile, 4 waves (2x2) of 64x64, BK=64 kf-split LDS, mfma
// 16x16x32 bf16. v2: TRUE double buffer + 2-phase pipeline (T3 minimum):
// stage(t+1) issued AFTER the barrier, compute(t) runs between issue and the
// next barrier's vmcnt-drain -> HBM latency hidden behind compute instead of
// exposed serially (old: barrier; stage; barrier(drain); compute = 1-phase).
// Hazards: at barrier_t the only outstanding loads are stage(t)'s (needed);
// stage(t+1) overwrites buf(t-1) only after barrier_t confirms readers done.
// LDS 64KB/block, 2 blocks/CU = 128KB.
template <bool OUT_BF16>
__global__ __launch_bounds__(256, 2) void k_gemm(
    const bf16* __restrict__ A, const bf16* __restrict__ Bt,
    const float* __restrict__ bias, void* __restrict__ Cout,
    int M, int N, int K) {
    __shared__ __align__(16) bf16 lA[2][8192];   // [buf][kf*4096 + row*32 + c]
    __shared__ __align__(16) bf16 lB[2][8192];
    int tid = threadIdx.x;
    int wid = tid >> 6, lane = tid & 63;
    int quad = lane >> 4, l16 = lane & 15;
    int bm = blockIdx.y * 128, bn = blockIdx.x * 128;
    int wm = (wid >> 1) * 64, wn = (wid & 1) * 64;

    f32x4 zero = {0.f, 0.f, 0.f, 0.f};
    f32x4 acc[4][4];
#pragma unroll
    for (int i = 0; i < 4; ++i)
#pragma unroll
        for (int j = 0; j < 4; ++j) acc[i][j] = zero;

    auto stage = [&](int k0, int buf) {
#pragma unroll
        for (int i = 0; i < 4; ++i) {
            int j = (wid * 4 + i) * 64 + lane;          // 0..1023
            int kf = j >> 9, row = (j & 511) >> 2, c8 = (j & 3) * 8;
            gld_lds16(A  + (size_t)(bm + row) * K + k0 + kf * 32 + c8, &lA[buf][0] + (wid * 4 + i) * 512);
            gld_lds16(Bt + (size_t)(bn + row) * K + k0 + kf * 32 + c8, &lB[buf][0] + (wid * 4 + i) * 512);
        }
    };

    stage(0, 0);
    int cur = 0;
    for (int k0 = 0; k0 < K; k0 += 64) {
        __syncthreads();                    // vmcnt(0)+barrier: buf[cur] ready;
                                            // buf[cur^1] readers all done
        if (k0 + 64 < K) stage(k0 + 64, cur ^ 1);   // in flight across compute
#pragma unroll
        for (int kk = 0; kk < 2; ++kk) {
            bf16x8 af[4], bg[4];
#pragma unroll
            for (int i = 0; i < 4; ++i) {
                af[i] = *(const bf16x8*)(&lA[cur][kk * 4096 + (wm + i * 16 + l16) * 32 + quad * 8]);
                bg[i] = *(const bf16x8*)(&lB[cur][kk * 4096 + (wn + i * 16 + l16) * 32 + quad * 8]);
            }
#pragma unroll
            for (int i = 0; i < 4; ++i)
#pragma unroll
                for (int j = 0; j < 4; ++j)
                    acc[i][j] = __builtin_amdgcn_mfma_f32_16x16x32_bf16(af[i], bg[j], acc[i][j], 0, 0, 0);
        }
        cur ^= 1;
    }
#pragma unroll
    for (int i = 0; i < 4; ++i) {
#pragma unroll
        for (int j = 0; j < 4; ++j) {
            int col = bn + wn + j * 16 + l16;
            float bv = bias ? bias[col] : 0.f;
#pragma unroll
            for (int r = 0; r < 4; ++r) {
                int row = bm + wm + i * 16 + quad * 4 + r;
                float v = acc[i][j][r] + bv;
                if (OUT_BF16) ((bf16*)Cout)[(size_t)row * N + col] = (bf16)v;
                else          ((float*)Cout)[(size_t)row * N + col] = v;
            }
        }
    }
}

// ---------------- flash attention (v11, reverted: best measured 79.8us) -----
//  * acc-init via MFMA C-operand (MINIT loop-invariant in 4 VGPRs).
//  * V single-buffered, staged at iteration top, consumed behind
//    s_waitcnt vmcnt(2) (V's 2 loads oldest; K prefetch stays in flight).
//  * lP kf-split [32][36]; K double-buffer + XOR swizzle both-sides;
//    exp2 domain; MFMA-ones rowsum; heavy-qb-first static block mapping
//    (bh->XCD spread keeps each XCD's 8 bh in its 4MB L2 — work-stealing
//    broke this: FETCH 25.6->100MB, +35us. Do not re-attempt without
//    locality preservation).
__global__ __launch_bounds__(256, 4) void k_attn(
    const bf16* __restrict__ qkv,   // [B*T][3072]
    const bf16* __restrict__ vt,    // [(bh*64+d)*2048 + t]
    bf16* __restrict__ y) {         // [B*T][1024]
    __shared__ __align__(16) bf16 lK[2][4096];
    __shared__ __align__(16) bf16 lV[4096];
    __shared__ __align__(16) bf16 lP[4][32 * 36];   // [q 32][t 32+4 pad] per kf

    const int T = 2048, CQ = 3072;
    int tid = threadIdx.x, wid = tid >> 6, lane = tid & 63;
    int quad = lane >> 4, l16 = lane & 15;
    // bh spread so each XCD's 8 bh (4MB K+V) fits its L2; heavy qb first.
    int x = blockIdx.x;
    int bh = ((x & 7) << 3) | ((x >> 3) & 7);
    int qb = 15 - (x >> 6);                    // 128-row block index, 0..15
    int b = bh >> 4, h = bh & 15;
    int q0 = qb * 128;
    int rb = qb * 4 + wid;                     // this wave's 32-row block idx
    int mdiag = rb >> 1;                       // k-tile containing diagonal
    int ntiles = qb * 2 + 2;                   // tiles staged by this block

    const bf16* qbase = qkv + (size_t)(b * T + q0 + wid * 32) * CQ + h * 64;
    const bf16* kbase = qkv + (size_t)(b * T) * CQ + 1024 + h * 64;
    const bf16* vbase = vt + (size_t)bh * 64 * T;
    bf16* lPw = lP[wid];

    // stage K tile kt into buffer buf: [row 64][col 64] bf16, 16B chunk index
    // XOR-swizzled by row&7 on the GLOBAL side (LDS dest stays linear).
    auto stageK = [&](int kt, int buf) {
        int t0 = kt * 64;
#pragma unroll
        for (int i = 0; i < 2; ++i) {
            int j = (wid * 2 + i) * 64 + lane;         // 0..511 16B-chunk id
            int r = j >> 3;                            // row (t)
            int cs = ((j ^ r) & 7) * 8;                // swizzled col offset
            gld_lds16(kbase + (size_t)(t0 + r) * CQ + cs, &lK[buf][(wid * 2 + i) * 512]);
        }
    };
    auto stageV = [&](int kt) {
        int t0 = kt * 64;
#pragma unroll
        for (int i = 0; i < 2; ++i) {
            int j = (wid * 2 + i) * 64 + lane;
            int r = j >> 3;                            // row (d)
            int cs = ((j ^ r) & 7) * 8;
            gld_lds16(vbase + (size_t)r * T + t0 + cs, &lV[(wid * 2 + i) * 512]);
        }
    };

    // Q B-frags (2 row-halves of this wave's 32 rows), prescaled into exp2 domain
    const float QSCALE = 0.125f * 1.44269504088896341f;
    bf16x8 qf[2][2];
#pragma unroll
    for (int qi = 0; qi < 2; ++qi)
#pragma unroll
        for (int kf = 0; kf < 2; ++kf) {
            bf16x8 v = *(const bf16x8*)(qbase + (size_t)(qi * 16 + l16) * CQ + kf * 32 + quad * 8);
#pragma unroll
            for (int j = 0; j < 8; ++j) v[j] = (bf16)((float)v[j] * QSCALE);
            qf[qi][kf] = v;
        }

    f32x4 zero = {0.f, 0.f, 0.f, 0.f};
    f32x4 minit = {-14.4269504089f, -14.4269504089f, -14.4269504089f, -14.4269504089f};
    f32x4 o[2][4];
    f32x4 ls[2];
#pragma unroll
    for (int qi = 0; qi < 2; ++qi) {
        ls[qi] = zero;
#pragma unroll
        for (int i = 0; i < 4; ++i) o[qi][i] = zero;
    }
    bf16x8 ones;
#pragma unroll
    for (int j = 0; j < 8; ++j) ones[j] = (bf16)1.0f;

    stageK(0, 0);                              // 2 loads outstanding
    for (int kt = 0; kt < ntiles; ++kt) {
        __syncthreads();                       // K(kt) landed everywhere; all
                                               // waves done reading V(kt-1)
        stageV(kt);                            // 2 loads (oldest outstanding)
        int knext = (kt + 1 < ntiles) ? kt + 1 : kt;   // last iter: restage kt
        stageK(knext, (kt + 1) & 1);           // 2 loads (newest; stay in flight)
        if (kt > mdiag) continue;              // no live cols; still hit barriers
        const bf16* Kb = lK[kt & 1];
        bool diag = (kt == mdiag);
        bool half = diag && !(rb & 1);         // even rb: only t 0..31 live
        int in_hi = half ? 2 : 4;

        // S^T = K (Q*log2e/8)^T - 10*log2e : lane holds q=l16, t=in*16+quad*4+r
        // First MFMA takes MINIT as C directly — no per-tile acc-init movs.
        f32x4 s[2][4];
#pragma unroll
        for (int in = 0; in < 4; ++in) {
            if (in >= in_hi) break;
            bf16x8 kb0 = *(const bf16x8*)(Kb + (in * 16 + l16) * 64 + ((quad ^ (l16 & 7)) * 8));
            bf16x8 kb1 = *(const bf16x8*)(Kb + (in * 16 + l16) * 64 + (((4 + quad) ^ (l16 & 7)) * 8));
#pragma unroll
            for (int qi = 0; qi < 2; ++qi) {
                f32x4 t0 = __builtin_amdgcn_mfma_f32_16x16x32_bf16(kb0, qf[qi][0], minit, 0, 0, 0);
                s[qi][in] = __builtin_amdgcn_mfma_f32_16x16x32_bf16(kb1, qf[qi][1], t0, 0, 0, 0);
            }
        }

        int rl0 = (rb * 32) - kt * 64;         // q offset rel to tile t-base
#pragma unroll
        for (int kf = 0; kf < 2; ++kf) {
            // p = exp2(S) for this kf's 32 t-cols; causal mask on diag;
            // P -> lP[32][36] as packed b64
#pragma unroll
            for (int qi = 0; qi < 2; ++qi) {
                int qloc = rl0 + qi * 16 + l16;
#pragma unroll
                for (int in2 = 0; in2 < 2; ++in2) {
                    int in = kf * 2 + in2;
                    bf16x4 pk4;
                    if (in >= in_hi) {
                        pk4[0] = pk4[1] = pk4[2] = pk4[3] = (bf16)0.f;
                    } else {
#pragma unroll
                        for (int r = 0; r < 4; ++r) {
                            float e = __builtin_amdgcn_exp2f(s[qi][in][r]);
                            if (diag) {
                                int tloc = kf * 32 + in2 * 16 + quad * 4 + r;
                                if (tloc > qloc) e = 0.f;
                            }
                            pk4[r] = (bf16)e;
                        }
                    }
                    *(bf16x4*)(lPw + (qi * 16 + l16) * 36 + in2 * 16 + quad * 4) = pk4;
                }
            }
            if (kf == 0)  // V(kt)'s 2 loads are the oldest outstanding; K
                          // prefetch (2 newest) stays in flight (T4 counted)
                asm volatile("s_waitcnt vmcnt(2)" ::: "memory");
            // V B-frags for this kf (swizzled reads from single buffer)
            bf16x8 vb[4];
#pragma unroll
            for (int dn = 0; dn < 4; ++dn)
                vb[dn] = *(const bf16x8*)(lV + (dn * 16 + l16) * 64 + (((kf * 4 + quad) ^ (l16 & 7)) * 8));
            // P A-frags (same-wave LDS), O += P V, rowsum += P*ones
#pragma unroll
            for (int qi = 0; qi < 2; ++qi) {
                bf16x8 pa = *(const bf16x8*)(lPw + (qi * 16 + l16) * 36 + quad * 8);
                ls[qi] = __builtin_amdgcn_mfma_f32_16x16x32_bf16(pa, ones, ls[qi], 0, 0, 0);
#pragma unroll
                for (int dn = 0; dn < 4; ++dn)
                    o[qi][dn] = __builtin_amdgcn_mfma_f32_16x16x32_bf16(pa, vb[dn], o[qi][dn], 0, 0, 0);
            }
        }
    }

    // epilogue: ls[qi][r] = rowsum for q=quad*4+r — exact same C-layout rows
    // as o[qi][dn][r]; no cross-lane reduction needed.
#pragma unroll
    for (int qi = 0; qi < 2; ++qi)
#pragma unroll
        for (int r = 0; r < 4; ++r) {
            float li = 1.f / ls[qi][r];
            int row = q0 + wid * 32 + qi * 16 + quad * 4 + r;
#pragma unroll
            for (int dn = 0; dn < 4; ++dn) {
                float v = o[qi][dn][r] * li;
                y[(size_t)(b * T + row) * 1024 + h * 64 + dn * 16 + l16] = (bf16)v;
            }
        }
}

extern "C" void kernel_launch(void* const* d_in, const int* in_sizes, int n_in,
                              void* d_out, int out_size, void* d_ws, size_t ws_size,
                              hipStream_t stream) {
    const float* x     = (const float*)d_in[0];
    const float* w_qkv = (const float*)d_in[1];
    const float* b_qkv = (const float*)d_in[2];
    const float* w_out = (const float*)d_in[3];
    const float* b_out = (const float*)d_in[4];
    float* out = (float*)d_out;

    const int B = 4, T = 2048, C = 1024, H = 16;
    const int M = B * T;  // 8192

    // workspace layout (88 MB total); vt aliases xb (xb dead after GEMM1)
    char* ws = (char*)d_ws;
    bf16* xb    = (bf16*)(ws);                        // 16 MB
    bf16* wqkvT = (bf16*)(ws + (16ull << 20));        //  6 MB
    bf16* woutT = (bf16*)(ws + (22ull << 20));        //  2 MB
    bf16* qkvb  = (bf16*)(ws + (24ull << 20));        // 48 MB
    bf16* yb    = (bf16*)(ws + (72ull << 20));        // 16 MB
    bf16* vtb   = xb;

    k_cvt_bf16<<<(M * C / 4 + 255) / 256, 256, 0, stream>>>(x, xb, M * C / 4);
    k_transpose_cvt<<<dim3(3 * C / 64, C / 64), 256, 0, stream>>>(w_qkv, wqkvT, C, 3 * C);
    k_transpose_cvt<<<dim3(C / 64, C / 64), 256, 0, stream>>>(w_out, woutT, C, C);
    k_gemm<true><<<dim3(3 * C / 128, M / 128), 256, 0, stream>>>(xb, wqkvT, b_qkv, qkvb, M, 3 * C, C);
    k_transpose_v<<<dim3(T / 64, B * H), 256, 0, stream>>>(qkvb, vtb);
    k_attn<<<dim3(1024, 1), 256, 0, stream>>>(qkvb, vtb, yb);
    k_gemm<false><<<dim3(C / 128, M / 128), 256, 0, stream>>>(yb, woutT, b_out, out, M, C, C);
}